// Round 5
// baseline (470.697 us; speedup 1.0000x reference)
//
#include <hip/hip_runtime.h>
#include <math.h>

#define T_LEN    16000
#define T_LEN4   4000          // float4 count per row
#define THREADS  256           // 4 waves/block; each wave owns ONE row
#define WTILE4   256           // float4 per wave-tile (64 lanes * 4)
#define NTILES   16            // 16*1024 = 16384 >= 16000; tail: lanes 0..39 of tile 15
#define EPS_F    1e-6f

// Wave-autonomous rows: one wave = one row, scan via __shfl only.
// ZERO __syncthreads, ZERO bulk LDS, no block-wide re-convergence, no block
// cycling: grid = 1024 blocks * 4 waves = 4096 rows; launch_bounds(256,4)
// -> 16 waves/CU resident = ALL rows of a CU live from t=0. Each wave keeps a
// 1-tile register prefetch in flight (4KB), 16 waves/CU -> 64KB in flight/CU,
// far above the ~9KB needed to sustain HBM BW at ~900cy latency.
__launch_bounds__(THREADS, 4)
__global__ void pcen_kernel(const float* __restrict__ x,
                            const float* __restrict__ alpha,
                            const float* __restrict__ delta,
                            const float* __restrict__ root,
                            const float* __restrict__ ema_w,
                            float* __restrict__ out, int C, int rows) {
    const int lane = threadIdx.x & 63;
    const int row  = blockIdx.x * (THREADS / 64) + (threadIdx.x >> 6);
    if (row >= rows) return;               // no barriers anywhere -> safe
    const int c = row % C;

    const float s   = fminf(fmaxf(ema_w[c], 0.0f), 1.0f);
    const float q   = 1.0f - s;
    const float a_c = fminf(alpha[c], 1.0f);
    const float r   = 1.0f / fmaxf(root[c], 1.0f);
    const float d   = delta[c];
    const float dr  = powf(d, r);
    const float q16 = powf(q, 16.0f);      // composed A over a full 16-elem chunk
    const bool  sqrt_path = (r == 0.5f);   // root=2 -> (v+d)^r is a sqrt

    const float4* x4 = (const float4*)(x   + (size_t)row * T_LEN);
    float4*       o4 = (float4*)      (out + (size_t)row * T_LEN);

    float e_carry = 0.0f;

    auto loadt = [&](int t, float4& r0, float4& r1, float4& r2, float4& r3) {
        const int b4 = t * WTILE4 + lane * 4;       // 64B contiguous per lane
        if (b4 < T_LEN4) { r0 = x4[b4]; r1 = x4[b4+1]; r2 = x4[b4+2]; r3 = x4[b4+3]; }
        else             { r0 = r1 = r2 = r3 = make_float4(1.f, 1.f, 1.f, 1.f); }
    };

    auto body = [&](int t, float4& c0, float4& c1, float4& c2, float4& c3,
                    bool pref, float4& n0, float4& n1, float4& n2, float4& n3) {
        const int  b4    = t * WTILE4 + lane * 4;
        const bool valid = (b4 < T_LEN4);           // all-or-nothing per lane
        float xv[16] = { c0.x, c0.y, c0.z, c0.w,  c1.x, c1.y, c1.z, c1.w,
                         c2.x, c2.y, c2.z, c2.w,  c3.x, c3.y, c3.z, c3.w };

        // prefetch next tile; no barrier ever drains it (there are no barriers)
        if (pref) loadt(t + 1, n0, n1, n2, n3);

        // ---- pass 1: compose (A,b) over this lane's 16 elements ----
        const bool ft = (t == 0) && (lane == 0);    // first element of the row
        float la = ft ? 0.0f  : q16;                // A = 0*q^15 or q^16
        float lb = ft ? xv[0] : s * xv[0];
        #pragma unroll
        for (int j = 1; j < 16; ++j) lb = fmaf(q, lb, s * xv[j]);

        // ---- wave-inclusive scan (Hillis-Steele over 64 lanes, shfl only) ----
        #pragma unroll
        for (int off = 1; off < 64; off <<= 1) {
            float ua = __shfl_up(la, off);
            float ub = __shfl_up(lb, off);
            if (lane >= off) { lb = fmaf(la, ub, lb); la *= ua; }
        }

        // ---- lane-exclusive prefix -> EMA state entering this chunk ----
        float ea = __shfl_up(la, 1);
        float eb = __shfl_up(lb, 1);
        float a_ex = (lane == 0) ? 1.0f : ea;
        float b_ex = (lane == 0) ? 0.0f : eb;
        float e = fmaf(a_ex, e_carry, b_ex);

        // ---- wave total (lane 63 inclusive) -> carry for next tile ----
        float ta = __shfl(la, 63);
        float tb = __shfl(lb, 63);
        e_carry = fmaf(ta, e_carry, tb);

        // ---- pass 2: EMA recurrence + pointwise in registers; store direct ----
        if (valid) {
            if (sqrt_path) {
                #pragma unroll
                for (int j = 0; j < 16; ++j) {
                    float xvj = xv[j];
                    e = (ft && j == 0) ? xvj : fmaf(q, e, s * xvj);
                    float lge = log2f(EPS_F + e);
                    float v   = xvj * exp2f(-a_c * lge);
                    xv[j] = sqrtf(v + d) - dr;
                }
            } else {
                #pragma unroll
                for (int j = 0; j < 16; ++j) {
                    float xvj = xv[j];
                    e = (ft && j == 0) ? xvj : fmaf(q, e, s * xvj);
                    float lge = log2f(EPS_F + e);
                    float v   = xvj * exp2f(-a_c * lge);
                    xv[j] = exp2f(r * log2f(v + d)) - dr;
                }
            }
            o4[b4 + 0] = make_float4(xv[ 0], xv[ 1], xv[ 2], xv[ 3]);
            o4[b4 + 1] = make_float4(xv[ 4], xv[ 5], xv[ 6], xv[ 7]);
            o4[b4 + 2] = make_float4(xv[ 8], xv[ 9], xv[10], xv[11]);
            o4[b4 + 3] = make_float4(xv[12], xv[13], xv[14], xv[15]);
        }
    };

    // 16 tiles, two named register sets (rule #20: no runtime-indexed arrays)
    float4 A0, A1, A2, A3, B0, B1, B2, B3;
    loadt(0, A0, A1, A2, A3);
    #pragma unroll
    for (int tt = 0; tt < NTILES; tt += 2) {
        body(tt,     A0, A1, A2, A3, true,           B0, B1, B2, B3);
        body(tt + 1, B0, B1, B2, B3, tt + 2 < NTILES, A0, A1, A2, A3);
    }
}

extern "C" void kernel_launch(void* const* d_in, const int* in_sizes, int n_in,
                              void* d_out, int out_size, void* d_ws, size_t ws_size,
                              hipStream_t stream) {
    const float* x     = (const float*)d_in[0];
    const float* alpha = (const float*)d_in[1];
    const float* delta = (const float*)d_in[2];
    const float* root  = (const float*)d_in[3];
    const float* ema_w = (const float*)d_in[4];
    float* out = (float*)d_out;

    const int C    = in_sizes[1];               // 128
    const int rows = in_sizes[0] / T_LEN;       // B*C = 4096
    const int blocks = (rows + 3) / 4;          // 4 rows (waves) per block

    pcen_kernel<<<blocks, THREADS, 0, stream>>>(x, alpha, delta, root, ema_w, out, C, rows);
}